// Round 9
// baseline (833.172 us; speedup 1.0000x reference)
//
#include <hip/hip_runtime.h>

constexpr int   BB    = 32;
constexpr int   NPP   = 1369;
constexpr int   DIMC  = 768;
constexpr int   NCLSC = 200;
constexpr int   KP    = 5;
constexpr int   CC    = 201;
constexpr int   CKC   = 1005;
constexpr int   NPAD  = 1024;              // padded proto rows for MFMA tiles
constexpr int   NTOK  = BB * NPP;          // 43808
constexpr float EPSF  = 1e-8f;
constexpr int   PWIN  = 128;               // pnew row window
constexpr int   MTILES = 343;              // ceil(43808/128)

typedef __attribute__((ext_vector_type(8))) short bf16x8;
typedef __attribute__((ext_vector_type(4))) float f32x4;

// ---- output layout (float units) ----
constexpr size_t O_LOG = 0;
constexpr size_t O_IMG = (size_t)NTOK * CKC;
constexpr size_t O_CLS = O_IMG + (size_t)BB * CKC;
constexpr size_t O_PSE = O_CLS + (size_t)BB * NCLSC;
constexpr size_t O_PRO = O_PSE + (size_t)NTOK;

// ---- ws layout (float units; doubles at even offsets) ----
constexpr size_t W_PRONBF = 0;                               // ushort[1024*768]
constexpr size_t W_INVN   = W_PRONBF + (size_t)NPAD*DIMC/2;  // float[NTOK]
constexpr size_t W_MU     = W_INVN + NTOK;                   // double[768]
constexpr size_t W_COLS   = W_MU + 2*DIMC;                   // double[768]   zero-group start
constexpr size_t W_VBUF   = W_COLS + 2*DIMC;                 // double[11*768]
constexpr size_t W_SSUM   = W_VBUF + 2*11*DIMC;              // double[16]
constexpr size_t W_TSUM   = W_SSUM + 32;                     // float[201]
constexpr size_t W_NC     = W_TSUM + CC;                     // int[201]
constexpr size_t W_FILL   = W_NC + CC;                       // int[201]
constexpr size_t W_PRES   = W_FILL + CC;                     // int[201]
constexpr size_t ZG_LEN   = (W_PRES + CC) - W_COLS;
constexpr size_t W_CSQ    = W_PRES + CC;                     // float[1005] (unused now)
constexpr size_t W_U      = ((W_CSQ + CKC) + 1) & ~(size_t)1;// double[NTOK]
constexpr size_t W_PART   = W_U + 2*NTOK;                    // double[1536]
constexpr size_t W_SCAL   = W_PART + 2*1536;                 // double[8]
constexpr size_t W_Q      = W_SCAL + 16;                     // float[NTOK*5] (segment-ordered)
constexpr size_t W_PNEW   = W_Q + (size_t)NTOK*KP;           // float[201*5*768]
constexpr size_t W_PLAB   = W_PNEW + (size_t)CC*KP*DIMC;     // int[NTOK]
constexpr size_t W_OFFS   = W_PLAB + NTOK;                   // int[256]
constexpr size_t W_RLST   = W_OFFS + 256;                    // int[NTOK]
constexpr size_t W_XBF    = ((W_RLST + NTOK) + 3) & ~(size_t)3; // ushort[(NTOK+128)*768]
constexpr size_t W_END_BIG  = W_XBF + (size_t)(NTOK + 128)*DIMC/2; // pad rows for M-tail
constexpr size_t W_PRON32   = W_XBF;                          // float[CKC*768] (fallback)
constexpr size_t W_END_FALL = W_PRON32 + (size_t)CKC*DIMC;

__device__ __forceinline__ unsigned short f2bf(float x) {
    unsigned u = __float_as_uint(x);
    unsigned r = (u + 0x7fffu + ((u >> 16) & 1u)) >> 16;   // RNE
    return (unsigned short)r;
}

// async global->LDS, 16B per lane; LDS dest must be wave-uniform base
typedef __attribute__((address_space(3))) unsigned int as3_u32;
typedef __attribute__((address_space(1))) unsigned int as1_u32;
__device__ __forceinline__ void gload16(const unsigned short* g, unsigned short* l) {
    __builtin_amdgcn_global_load_lds((as1_u32*)g, (as3_u32*)l, 16, 0, 0);
}

__global__ void fill_zero(float* p, int n) {
    int i = blockIdx.x * 256 + threadIdx.x;
    if (i < n) p[i] = 0.0f;
}

// per-row 1/clip(||x||) + fp64 column sums + optional bf16 copy of X.
// float4 loads (16B/lane), ushort4 bf16 stores. Lane owns cols 4l+256j+t.
__global__ __launch_bounds__(256) void tok_stats(const float* __restrict__ X,
                                                 float* __restrict__ invn,
                                                 double* __restrict__ colsD,
                                                 unsigned short* __restrict__ xbf) {
    const int lane = threadIdx.x & 63;
    const int gw   = blockIdx.x * 4 + (threadIdx.x >> 6);
    double cacc[3][4];
    #pragma unroll
    for (int j = 0; j < 3; j++)
        #pragma unroll
        for (int t = 0; t < 4; t++) cacc[j][t] = 0.0;
    for (int n = gw; n < NTOK; n += 1024) {
        const float4* row = (const float4*)(X + (size_t)n * DIMC);
        float s = 0.0f;
        float4 xv[3];
        #pragma unroll
        for (int j = 0; j < 3; j++) {
            xv[j] = row[lane + 64*j];
            s = fmaf(xv[j].x, xv[j].x, s); s = fmaf(xv[j].y, xv[j].y, s);
            s = fmaf(xv[j].z, xv[j].z, s); s = fmaf(xv[j].w, xv[j].w, s);
            cacc[j][0] += (double)xv[j].x; cacc[j][1] += (double)xv[j].y;
            cacc[j][2] += (double)xv[j].z; cacc[j][3] += (double)xv[j].w;
        }
        if (xbf) {
            unsigned short* orow = xbf + (size_t)n * DIMC;
            #pragma unroll
            for (int j = 0; j < 3; j++) {
                ushort4 pk;
                pk.x = f2bf(xv[j].x); pk.y = f2bf(xv[j].y);
                pk.z = f2bf(xv[j].z); pk.w = f2bf(xv[j].w);
                *(ushort4*)(orow + 4*(lane + 64*j)) = pk;
            }
        }
        #pragma unroll
        for (int o = 32; o >= 1; o >>= 1) s += __shfl_xor(s, o);
        if (lane == 0) invn[n] = 1.0f / fmaxf(sqrtf(s), EPSF);
    }
    #pragma unroll
    for (int j = 0; j < 3; j++)
        #pragma unroll
        for (int t = 0; t < 4; t++)
            atomicAdd(&colsD[4*lane + 256*j + t], cacc[j][t]);
}

// normalize prototypes -> bf16 (padded rows zeroed) and optional f32 copy
__global__ __launch_bounds__(256) void proto_norm(const float* __restrict__ P,
                                                  unsigned short* __restrict__ pbf,
                                                  float* __restrict__ p32) {
    const int lane = threadIdx.x & 63;
    const int gw   = blockIdx.x * 4 + (threadIdx.x >> 6);
    for (int j = gw; j < NPAD; j += 256) {
        unsigned short* obf = pbf + (size_t)j * DIMC;
        if (j >= CKC) {
            #pragma unroll
            for (int t = 0; t < 12; t++) obf[lane + 64*t] = 0;
            continue;
        }
        const float* row = P + (size_t)j * DIMC;
        float x[12]; float s = 0.0f;
        #pragma unroll
        for (int t = 0; t < 12; t++) { x[t] = row[lane + 64*t]; s = fmaf(x[t], x[t], s); }
        #pragma unroll
        for (int o = 32; o >= 1; o >>= 1) s += __shfl_xor(s, o);
        float nrm = fmaxf(sqrtf(s), EPSF);
        #pragma unroll
        for (int t = 0; t < 12; t++) {
            float nv = x[t] / nrm;
            obf[lane + 64*t] = f2bf(nv);
            if (p32) p32[(size_t)j * DIMC + lane + 64*t] = nv;
        }
    }
}

// Tiled bf16 MFMA GEMM with global_load_lds staging (m97 structure):
// C = Xbf * Pbf^T, fused scale+invn + image-mean partials.
// 128x128 tile, BK=32, 4 waves, linear LDS [128][32], chunked XCD swizzle.
__global__ __launch_bounds__(256) void logits_gemm(
        const unsigned short* __restrict__ Xbf,
        const unsigned short* __restrict__ Pbf,
        const float* __restrict__ invn,
        const float* __restrict__ scale_p,
        float* __restrict__ out,
        float* __restrict__ img) {
    __shared__ unsigned short As[128 * 32];
    __shared__ unsigned short Bs[128 * 32];
    const int b   = blockIdx.x;                 // 0..2743
    const int swz = (b & 7) * MTILES + (b >> 3);  // bijective: 2744 = 8*343
    const int row_t = swz >> 3, col_t = swz & 7;
    const int row0 = row_t * 128, col0 = col_t * 128;
    const int tid = threadIdx.x, lane = tid & 63, wid = tid >> 6;
    const int wm = (wid >> 1) * 64, wn = (wid & 1) * 64;
    const int fr = lane & 15, fq = lane >> 4;

    f32x4 acc[4][4] = {};

    // staging geometry: wave wid stages rows [wid*32, wid*32+32) of A and B,
    // two 16-row instructions each; lane l covers row +l/4, 16B chunk (l&3).
    const int w32 = wid * 32;
    const int lrow = lane >> 2, lk = (lane & 3) * 8;
    const unsigned short* aS0 = Xbf + (size_t)(row0 + w32 + lrow) * DIMC + lk;
    const unsigned short* aS1 = aS0 + (size_t)16 * DIMC;
    const unsigned short* bS0 = Pbf + (size_t)(col0 + w32 + lrow) * DIMC + lk;
    const unsigned short* bS1 = bS0 + (size_t)16 * DIMC;
    unsigned short* aD0 = &As[(w32)      * 32];
    unsigned short* aD1 = &As[(w32 + 16) * 32];
    unsigned short* bD0 = &Bs[(w32)      * 32];
    unsigned short* bD1 = &Bs[(w32 + 16) * 32];

    for (int ks = 0; ks < DIMC / 32; ks++) {
        __syncthreads();                      // prior reads done before overwrite
        gload16(aS0 + ks * 32, aD0);
        gload16(aS1 + ks * 32, aD1);
        gload16(bS0 + ks * 32, bD0);
        gload16(bS1 + ks * 32, bD1);
        __syncthreads();                      // drains vmcnt -> LDS ready
        bf16x8 af[4], bfr[4];
        #pragma unroll
        for (int m = 0; m < 4; m++)
            af[m] = *(const bf16x8*)(As + (wm + m * 16 + fr) * 32 + fq * 8);
        #pragma unroll
        for (int n = 0; n < 4; n++)
            bfr[n] = *(const bf16x8*)(Bs + (wn + n * 16 + fr) * 32 + fq * 8);
        #pragma unroll
        for (int m = 0; m < 4; m++)
            #pragma unroll
            for (int n = 0; n < 4; n++)
                acc[m][n] = __builtin_amdgcn_mfma_f32_16x16x32_bf16(af[m], bfr[n], acc[m][n], 0, 0, 0);
    }

    const float sc = *scale_p;
    #pragma unroll
    for (int m = 0; m < 4; m++) {
        const int rbase = row0 + wm + m * 16 + fq * 4;
        float fin[4];
        #pragma unroll
        for (int rr = 0; rr < 4; rr++) {
            int rrow = rbase + rr;
            fin[rr] = (rrow < NTOK) ? sc * invn[rrow] : 0.0f;
        }
        const int strip0 = row0 + wm + m * 16;
        const bool sameImg = ((strip0 / NPP) == ((strip0 + 15) / NPP)) && (strip0 + 15) < NTOK;
        const int bimg = strip0 / NPP;
        #pragma unroll
        for (int n = 0; n < 4; n++) {
            const int col = col0 + wn + n * 16 + fr;
            const bool cok = col < CKC;
            float csum = 0.0f;
            #pragma unroll
            for (int rr = 0; rr < 4; rr++) {
                int rrow = rbase + rr;
                float v = fin[rr] * acc[m][n][rr];
                if (cok && rrow < NTOK) out[(size_t)rrow * CKC + col] = v;
                csum += v;
            }
            if (sameImg) {
                csum += __shfl_xor(csum, 16);
                csum += __shfl_xor(csum, 32);
                if (lane < 16 && cok) atomicAdd(&img[bimg * CKC + col], csum);
            } else if (cok) {
                #pragma unroll
                for (int rr = 0; rr < 4; rr++) {
                    int rrow = rbase + rr;
                    if (rrow < NTOK)
                        atomicAdd(&img[(rrow / NPP) * CKC + col], fin[rr] * acc[m][n][rr]);
                }
            }
        }
    }
}

// fallback fp32 GEMM (used only when ws too small for Xbf)
__global__ __launch_bounds__(256) void gemm_logits(const float* __restrict__ X,
                                                   const float* __restrict__ Bn,
                                                   const float* __restrict__ invn,
                                                   const float* __restrict__ scale_p,
                                                   float* __restrict__ out) {
    __shared__ float As[32][68];
    __shared__ float Bs[32][68];
    const int tid = threadIdx.x;
    const int tx = tid & 15, ty = tid >> 4;
    const int row0 = blockIdx.x * 64;
    const int col0 = blockIdx.y * 64;
    const int lm = tid >> 2;
    const int kb = (tid & 3) * 8;
    float acc[4][4] = {};
    for (int k0 = 0; k0 < DIMC; k0 += 32) {
        float a[8], b[8];
        int ar = row0 + lm;
        if (ar < NTOK) {
            const float* ap = X + (size_t)ar * DIMC + k0 + kb;
            #pragma unroll
            for (int j = 0; j < 8; j++) a[j] = ap[j];
        } else {
            #pragma unroll
            for (int j = 0; j < 8; j++) a[j] = 0.0f;
        }
        int bc = col0 + lm;
        if (bc < CKC) {
            const float* bp = Bn + (size_t)bc * DIMC + k0 + kb;
            #pragma unroll
            for (int j = 0; j < 8; j++) b[j] = bp[j];
        } else {
            #pragma unroll
            for (int j = 0; j < 8; j++) b[j] = 0.0f;
        }
        __syncthreads();
        #pragma unroll
        for (int j = 0; j < 8; j++) As[kb + j][lm] = a[j];
        #pragma unroll
        for (int j = 0; j < 8; j++) Bs[kb + j][lm] = b[j];
        __syncthreads();
        #pragma unroll
        for (int kk = 0; kk < 32; kk++) {
            float av[4], bv[4];
            #pragma unroll
            for (int i = 0; i < 4; i++) av[i] = As[kk][ty*4 + i];
            #pragma unroll
            for (int j = 0; j < 4; j++) bv[j] = Bs[kk][tx*4 + j];
            #pragma unroll
            for (int i = 0; i < 4; i++)
                #pragma unroll
                for (int j = 0; j < 4; j++)
                    acc[i][j] = fmaf(av[i], bv[j], acc[i][j]);
        }
    }
    const float sc = *scale_p;
    #pragma unroll
    for (int i = 0; i < 4; i++) {
        int r = row0 + ty*4 + i;
        if (r >= NTOK) continue;
        float f = sc * invn[r];
        float* orow = out + (size_t)r * CKC;
        #pragma unroll
        for (int j = 0; j < 4; j++) {
            int c = col0 + tx*4 + j;
            if (c < CKC) orow[c] = f * acc[i][j];
        }
    }
}

__global__ void img_reduce(const float* __restrict__ logits, float* __restrict__ img) {
    int b = blockIdx.x, jc = blockIdx.y, nc = blockIdx.z;
    int j = jc * 256 + threadIdx.x;
    if (j >= CKC) return;
    int p0 = nc * 172, p1 = min(NPP, p0 + 172);
    const float* base = logits + (size_t)b * NPP * CKC + j;
    float s = 0.0f;
    for (int p = p0; p < p1; p++) s += base[(size_t)p * CKC];
    atomicAdd(&img[b * CKC + j], s);
}

__global__ __launch_bounds__(256) void img_final(float* __restrict__ img,
                                                 const float* __restrict__ sa,
                                                 float* __restrict__ cls) {
    int b = blockIdx.x;
    for (int i = threadIdx.x; i < CKC; i += 256)
        img[b * CKC + i] = img[b * CKC + i] / 1369.0f;
    __syncthreads();
    for (int c = threadIdx.x; c < NCLSC; c += 256) {
        float vv[KP]; float mx = -3.4e38f;
        #pragma unroll
        for (int k = 0; k < KP; k++) { vv[k] = sa[c * KP + k]; mx = fmaxf(mx, vv[k]); }
        float e[KP]; float s = 0.0f;
        #pragma unroll
        for (int k = 0; k < KP; k++) { e[k] = expf(vv[k] - mx); s += e[k]; }
        float cl = 0.0f;
        #pragma unroll
        for (int k = 0; k < KP; k++) {
            float sw = e[k] / s * 5.0f;
            cl += img[b * CKC + c * KP + k] * sw;
        }
        cls[b * NCLSC + c] = cl;
    }
}

__global__ void mu_final(const double* __restrict__ colsD, double* __restrict__ mu) {
    int d = threadIdx.x;
    mu[d] = colsD[d] / (double)NTOK;
}

// XLA uniform(lo=-0.99999994,hi=1) -> sqrt(2)*erfinv (Giles/XLA f32 polynomial)
__device__ __forceinline__ float bits_to_normal(unsigned bits) {
    float f = __uint_as_float((bits >> 9) | 0x3f800000u) - 1.0f;
    const float lo = -0.99999994f;
    float u = f * 2.0f + lo;
    u = fmaxf(lo, u);
    float w = -log1pf(-u * u);
    float p;
    if (w < 5.0f) {
        w -= 2.5f;
        p = 2.81022636e-08f;
        p = fmaf(p, w, 3.43273939e-07f);
        p = fmaf(p, w, -3.5233877e-06f);
        p = fmaf(p, w, -4.39150654e-06f);
        p = fmaf(p, w, 0.00021858087f);
        p = fmaf(p, w, -0.00125372503f);
        p = fmaf(p, w, -0.00417768164f);
        p = fmaf(p, w, 0.246640727f);
        p = fmaf(p, w, 1.50140941f);
    } else {
        w = sqrtf(w) - 3.0f;
        p = -0.000200214257f;
        p = fmaf(p, w, 0.000100950558f);
        p = fmaf(p, w, 0.00134934322f);
        p = fmaf(p, w, -0.00367342844f);
        p = fmaf(p, w, 0.00573950773f);
        p = fmaf(p, w, -0.0076224613f);
        p = fmaf(p, w, 0.00943887047f);
        p = fmaf(p, w, 1.00167406f);
        p = fmaf(p, w, 2.83297682f);
    }
    return 1.41421356237f * (p * u);
}

// jax threefry_partitionable, 32-bit: counter (hi=0, lo=i), sample = out0 ^ out1
#define TF_ROUND(r) { x0 += x1; x1 = (x1 << r) | (x1 >> (32 - r)); x1 ^= x0; }
__global__ void v0_gen(double* __restrict__ v) {
    int i = blockIdx.x * 256 + threadIdx.x;
    if (i >= DIMC) return;
    unsigned x0 = 0u, x1 = (unsigned)i;
    const unsigned k0 = 0u, k1 = 42u, k2 = k0 ^ k1 ^ 0x1BD11BDAu;
    x0 += k0; x1 += k1;
    TF_ROUND(13) TF_ROUND(15) TF_ROUND(26) TF_ROUND(6)
    x0 += k1; x1 += k2 + 1u;
    TF_ROUND(17) TF_ROUND(29) TF_ROUND(16) TF_ROUND(24)
    x0 += k2; x1 += k0 + 2u;
    TF_ROUND(13) TF_ROUND(15) TF_ROUND(26) TF_ROUND(6)
    x0 += k0; x1 += k1 + 3u;
    TF_ROUND(17) TF_ROUND(29) TF_ROUND(16) TF_ROUND(24)
    x0 += k1; x1 += k2 + 4u;
    TF_ROUND(13) TF_ROUND(15) TF_ROUND(26) TF_ROUND(6)
    x0 += k2; x1 += k0 + 5u;
    v[i] = (double)bits_to_normal(x0 ^ x1);
}

// One Gram application, fused: u = Xc*v_eff ; vnext += Xc^T u (all fp64 acc).
// float4 loads; ve held in registers (lane owns cols 4l+256j+t); wave-local
// mu.v reduce. Grid 1024 blocks for occupancy.
__global__ __launch_bounds__(256) void pca_pass(const float* __restrict__ X,
                                                const double* __restrict__ mu,
                                                const double* __restrict__ vraw,
                                                const double* __restrict__ Sin,
                                                double* __restrict__ vnext,
                                                double* __restrict__ Snext) {
    __shared__ double wacc[4][768];
    __shared__ double redw[4];
    const int tid = threadIdx.x, lane = tid & 63, wid = tid >> 6;
    const double S = *Sin;
    double ver[3][4];
    double mv = 0.0;
    #pragma unroll
    for (int j = 0; j < 3; j++)
        #pragma unroll
        for (int t = 0; t < 4; t++) {
            int c = 4*lane + 256*j + t;
            double x = vraw[c] - S * mu[c];
            ver[j][t] = x;
            mv += mu[c] * x;
        }
    #pragma unroll
    for (int o = 32; o >= 1; o >>= 1) mv += __shfl_xor(mv, o);
    const double muv = mv;

    double acc[3][4] = {};
    double usum = 0.0;
    const int gw = blockIdx.x * 4 + wid;
    for (int n = gw; n < NTOK; n += 4096) {
        const float4* row = (const float4*)(X + (size_t)n * DIMC);
        float4 xv[3];
        double s = 0.0;
        #pragma unroll
        for (int j = 0; j < 3; j++) {
            xv[j] = row[lane + 64*j];
            s = fma((double)xv[j].x, ver[j][0], s);
            s = fma((double)xv[j].y, ver[j][1], s);
            s = fma((double)xv[j].z, ver[j][2], s);
            s = fma((double)xv[j].w, ver[j][3], s);
        }
        #pragma unroll
        for (int o = 32; o >= 1; o >>= 1) s += __shfl_xor(s, o);
        double uu = s - muv;
        usum += uu;
        #pragma unroll
        for (int j = 0; j < 3; j++) {
            acc[j][0] = fma((double)xv[j].x, uu, acc[j][0]);
            acc[j][1] = fma((double)xv[j].y, uu, acc[j][1]);
            acc[j][2] = fma((double)xv[j].z, uu, acc[j][2]);
            acc[j][3] = fma((double)xv[j].w, uu, acc[j][3]);
        }
    }
    #pragma unroll
    for (int j = 0; j < 3; j++)
        #pragma unroll
        for (int t = 0; t < 4; t++)
            wacc[wid][4*lane + 256*j + t] = acc[j][t];
    if (lane == 0) redw[wid] = usum;
    __syncthreads();
    for (int c = tid; c < 768; c += 256)
        atomicAdd(&vnext[c], wacc[0][c] + wacc[1][c] + wacc[2][c] + wacc[3][c]);
    if (tid == 0) atomicAdd(Snext, redw[0] + redw[1] + redw[2] + redw[3]);
}

// final u = Xc*v_eff + per-block min/max/sumsq partials (float4, reg-ve)
__global__ __launch_bounds__(256) void u_final(const float* __restrict__ X,
                                               const double* __restrict__ mu,
                                               const double* __restrict__ vraw,
                                               const double* __restrict__ Sin,
                                               double* __restrict__ u,
                                               double* __restrict__ part) {
    __shared__ double wmin[4], wmax[4], wss[4];
    const int tid = threadIdx.x, lane = tid & 63, wid = tid >> 6;
    const double S = *Sin;
    double ver[3][4];
    double mv = 0.0;
    #pragma unroll
    for (int j = 0; j < 3; j++)
        #pragma unroll
        for (int t = 0; t < 4; t++) {
            int c = 4*lane + 256*j + t;
            double x = vraw[c] - S * mu[c];
            ver[j][t] = x;
            mv += mu[c] * x;
        }
    #pragma unroll
    for (int o = 32; o >= 1; o >>= 1) mv += __shfl_xor(mv, o);
    const double muv = mv;
    double lmin = 1e300, lmax = -1e300, lss = 0.0;
    for (int n = blockIdx.x * 4 + wid; n < NTOK; n += 2048) {
        const float4* row = (const float4*)(X + (size_t)n * DIMC);
        double s = 0.0;
        #pragma unroll
        for (int j = 0; j < 3; j++) {
            float4 xv = row[lane + 64*j];
            s = fma((double)xv.x, ver[j][0], s);
            s = fma((double)xv.y, ver[j][1], s);
            s = fma((double)xv.z, ver[j][2], s);
            s = fma((double)xv.w, ver[j][3], s);
        }
        #pragma unroll
        for (int o = 32; o >= 1; o >>= 1) s += __shfl_xor(s, o);
        double uu = s - muv;
        if (lane == 0) {
            u[n] = uu;
            lmin = fmin(lmin, uu); lmax = fmax(lmax, uu); lss = fma(uu, uu, lss);
        }
    }
    if (lane == 0) { wmin[wid] = lmin; wmax[wid] = lmax; wss[wid] = lss; }
    __syncthreads();
    if (tid == 0) {
        part[blockIdx.x]        = fmin(fmin(wmin[0], wmin[1]), fmin(wmin[2], wmin[3]));
        part[512 + blockIdx.x]  = fmax(fmax(wmax[0], wmax[1]), fmax(wmax[2], wmax[3]));
        part[1024 + blockIdx.x] = wss[0] + wss[1] + wss[2] + wss[3];
    }
}

__global__ __launch_bounds__(512) void final_scalars(const double* __restrict__ part,
                                                     double* __restrict__ scal,
                                                     const int* __restrict__ labels,
                                                     int* __restrict__ pres) {
    __shared__ double rmin[512], rmax[512], rss[512];
    int t = threadIdx.x;
    rmin[t] = part[t]; rmax[t] = part[512 + t]; rss[t] = part[1024 + t];
    __syncthreads();
    for (int s = 256; s > 0; s >>= 1) {
        if (t < s) {
            rmin[t] = fmin(rmin[t], rmin[t + s]);
            rmax[t] = fmax(rmax[t], rmax[t + s]);
            rss[t] += rss[t + s];
        }
        __syncthreads();
    }
    if (t == 0) {
        double nrm = fmax(sqrt(rss[0]), 1e-8);
        double Umin = rmin[0] / nrm;
        double Umax = rmax[0] / nrm;
        scal[1] = nrm;
        scal[2] = Umin;
        scal[3] = fmax(Umax - Umin, 1e-8);
    }
    if (t < BB) pres[labels[t]] = 1;
}

// pseudo labels + LDS-aggregated class histogram
__global__ __launch_bounds__(256) void pseudo_kernel(
        const double* __restrict__ u, const double* __restrict__ scal,
        const int* __restrict__ labels, float* __restrict__ pse,
        int* __restrict__ plab, int* __restrict__ Nc) {
    __shared__ int hist[CC];
    const int tid = threadIdx.x;
    for (int c = tid; c < CC; c += 256) hist[c] = 0;
    __syncthreads();
    int n = blockIdx.x * 256 + tid;
    if (n < NTOK) {
        double U  = u[n] / scal[1];
        double Us = (U - scal[2]) / scal[3];
        int lab = (Us <= 0.5) ? labels[n / NPP] : (CC - 1);
        pse[n] = (float)lab;
        plab[n] = lab;
        atomicAdd(&hist[lab], 1);
    }
    __syncthreads();
    for (int c = tid; c < CC; c += 256)
        if (hist[c] > 0) atomicAdd(&Nc[c], hist[c]);
}

__global__ void offs_scan(const int* __restrict__ Nc, int* __restrict__ offs) {
    if (threadIdx.x == 0) {
        int s = 0;
        for (int c = 0; c < CC; c++) { offs[c] = s; s += Nc[c]; }
        offs[CC] = s;
    }
}

// LDS-aggregated scatter
__global__ __launch_bounds__(256) void scatter_rows(
        const int* __restrict__ plab, const int* __restrict__ offs,
        int* __restrict__ fill, int* __restrict__ rlist) {
    __shared__ int hist[CC];
    __shared__ int base[CC];
    const int tid = threadIdx.x;
    for (int c = tid; c < CC; c += 256) hist[c] = 0;
    __syncthreads();
    int n = blockIdx.x * 256 + tid;
    int lab = -1, posl = 0;
    if (n < NTOK) {
        lab = plab[n];
        posl = atomicAdd(&hist[lab], 1);
    }
    __syncthreads();
    for (int c = tid; c < CC; c += 256) {
        int h = hist[c];
        if (h > 0) base[c] = atomicAdd(&fill[c], h);
    }
    __syncthreads();
    if (n < NTOK) rlist[offs[lab] + base[lab] + posl] = n;
}

// One block per fg class: fused sinkhorn over the class's qseg slice
__global__ __launch_bounds__(256) void sinkhorn_fused(
        const float* __restrict__ logits,
        const int* __restrict__ offs,
        const int* __restrict__ rlist,
        float* __restrict__ qseg) {
    const int c  = blockIdx.x;           // 0..NCLSC-1 (background excluded)
    const int i0 = offs[c], i1 = offs[c + 1];
    const int cnt = i1 - i0;
    if (cnt <= 0) return;
    const int tid = threadIdx.x;
    __shared__ float cs[KP];
    __shared__ float redk[KP][4];

    for (int i = i0 + tid; i < i1; i += 256) {
        int n = rlist[i];
        const float* lp = logits + (size_t)n * CKC + c * KP;
        #pragma unroll
        for (int k = 0; k < KP; k++) qseg[(size_t)i * KP + k] = expf(lp[k]);
    }
    const float Ncc = fmaxf((float)cnt, 1.0f);
    for (int it = 0; it < 3; it++) {
        __syncthreads();
        float lc[KP] = {};
        for (int i = i0 + tid; i < i1; i += 256) {
            #pragma unroll
            for (int k = 0; k < KP; k++) lc[k] += qseg[(size_t)i * KP + k];
        }
        #pragma unroll
        for (int k = 0; k < KP; k++) {
            float v = lc[k];
            #pragma unroll
            for (int o = 32; o >= 1; o >>= 1) v += __shfl_xor(v, o);
            if ((tid & 63) == 0) redk[k][tid >> 6] = v;
        }
        __syncthreads();
        if (tid == 0) {
            #pragma unroll
            for (int k = 0; k < KP; k++)
                cs[k] = fmaxf(redk[k][0] + redk[k][1] + redk[k][2] + redk[k][3], EPSF) * 5.0f;
        }
        __syncthreads();
        float inv_cs[KP];
        #pragma unroll
        for (int k = 0; k < KP; k++) inv_cs[k] = 1.0f / cs[k];
        const float outsc = (it == 2) ? ((float)cnt / Ncc) : (1.0f / Ncc);
        for (int i = i0 + tid; i < i1; i += 256) {
            float v[KP]; float rs = 0.0f;
            #pragma unroll
            for (int k = 0; k < KP; k++) { v[k] = qseg[(size_t)i*KP + k] * inv_cs[k]; rs += v[k]; }
            float f = outsc / fmaxf(rs, EPSF);
            #pragma unroll
            for (int k = 0; k < KP; k++) qseg[(size_t)i*KP + k] = v[k] * f;
        }
    }
}

// Windowed segmented P_new accumulation.
__global__ __launch_bounds__(256) void pnew_partial(
        const float* __restrict__ X,
        const float* __restrict__ invn,
        const float* __restrict__ qseg,
        const int* __restrict__ offs,
        const int* __restrict__ rlist,
        const int* __restrict__ plab,
        float* __restrict__ Pnew) {
    const int d = blockIdx.y * 256 + threadIdx.x;
    const int fgEnd = offs[CC - 1];
    int i0 = blockIdx.x * PWIN;
    if (i0 >= fgEnd) return;
    int i1 = min(i0 + PWIN, fgEnd);
    int curlab = -1;
    float acc[KP] = {};
    for (int i = i0; i < i1; i++) {
        int n = rlist[i];
        int lab = plab[n];
        if (lab != curlab) {
            if (curlab >= 0) {
                #pragma unroll
                for (int k = 0; k < KP; k++)
                    atomicAdd(&Pnew[((size_t)curlab * KP + k) * DIMC + d], acc[k]);
            }
            curlab = lab;
            #pragma unroll
            for (int k = 0; k < KP; k++) acc[k] = 0.0f;
        }
        float x = X[(size_t)n * DIMC + d] * invn[n];
        #pragma unroll
        for (int k = 0; k < KP; k++) acc[k] = fmaf(qseg[(size_t)i * KP + k], x, acc[k]);
    }
    if (curlab >= 0) {
        #pragma unroll
        for (int k = 0; k < KP; k++)
            atomicAdd(&Pnew[((size_t)curlab * KP + k) * DIMC + d], acc[k]);
    }
}

__global__ void proto_out(const float* __restrict__ proto, const float* __restrict__ Pnew,
                          const int* __restrict__ pres, float* __restrict__ outp) {
    int idx = blockIdx.x * 256 + threadIdx.x;
    if (idx >= CC * KP * DIMC) return;
    int c = idx / (KP * DIMC);
    float p = proto[idx];
    float r = p;
    if (pres[c]) {
        const float g = 0.99f;
        r = g * p + (1.0f - g) * Pnew[idx];
    }
    outp[idx] = r;
}

extern "C" void kernel_launch(void* const* d_in, const int* in_sizes, int n_in,
                              void* d_out, int out_size, void* d_ws, size_t ws_size,
                              hipStream_t stream) {
    const float* X      = (const float*)d_in[0];
    const int*   labels = (const int*)  d_in[1];
    const float* proto  = (const float*)d_in[2];
    const float* sa     = (const float*)d_in[3];
    const float* scale  = (const float*)d_in[4];
    float* out = (float*)d_out;
    float* ws  = (float*)d_ws;
    const bool big = ws_size >= W_END_BIG * sizeof(float);
    if (!big && ws_size < W_END_FALL * sizeof(float)) return;

    unsigned short* pronbf = (unsigned short*)(ws + W_PRONBF);
    float*  invn  = ws + W_INVN;
    double* mu    = (double*)(ws + W_MU);
    double* colsD = (double*)(ws + W_COLS);
    double* vbuf  = (double*)(ws + W_VBUF);
    double* Ssum  = (double*)(ws + W_SSUM);
    int*    Nc    = (int*)(ws + W_NC);
    int*    fill  = (int*)(ws + W_FILL);
    int*    pres  = (int*)(ws + W_PRES);
    double* u     = (double*)(ws + W_U);
    double* part  = (double*)(ws + W_PART);
    double* scal  = (double*)(ws + W_SCAL);
    float*  qseg  = ws + W_Q;
    float*  Pnew  = ws + W_PNEW;
    int*    plab  = (int*)(ws + W_PLAB);
    int*    offs  = (int*)(ws + W_OFFS);
    int*    rlist = (int*)(ws + W_RLST);
    unsigned short* xbf = big ? (unsigned short*)(ws + W_XBF) : nullptr;
    float*  pron32 = big ? nullptr : (ws + W_PRON32);

    // zero accumulators (ws is NOT re-poisoned between replays)
    fill_zero<<<((int)ZG_LEN + 255) / 256, 256, 0, stream>>>(ws + W_COLS, (int)ZG_LEN);
    fill_zero<<<(CC * KP * DIMC + 255) / 256, 256, 0, stream>>>(Pnew, CC * KP * DIMC);
    fill_zero<<<(BB * CKC + 255) / 256, 256, 0, stream>>>(out + O_IMG, BB * CKC);

    tok_stats<<<256, 256, 0, stream>>>(X, invn, colsD, xbf);
    proto_norm<<<64, 256, 0, stream>>>(proto, pronbf, pron32);
    if (big) {
        logits_gemm<<<MTILES * 8, 256, 0, stream>>>(xbf, pronbf, invn, scale,
                                                    out + O_LOG, out + O_IMG);
    } else {
        gemm_logits<<<dim3(685, 16), 256, 0, stream>>>(X, pron32, invn, scale, out + O_LOG);
        img_reduce<<<dim3(32, 4, 8), 256, 0, stream>>>(out + O_LOG, out + O_IMG);
    }
    img_final<<<32, 256, 0, stream>>>(out + O_IMG, sa, out + O_CLS);

    mu_final<<<1, 768, 0, stream>>>(colsD, mu);
    v0_gen<<<3, 256, 0, stream>>>(vbuf);
    for (int t = 0; t < 10; t++) {
        pca_pass<<<1024, 256, 0, stream>>>(X, mu, vbuf + (size_t)t * DIMC, Ssum + t,
                                           vbuf + (size_t)(t + 1) * DIMC, Ssum + t + 1);
    }
    u_final<<<512, 256, 0, stream>>>(X, mu, vbuf + (size_t)10 * DIMC, Ssum + 10, u, part);
    final_scalars<<<1, 512, 0, stream>>>(part, scal, labels, pres);
    pseudo_kernel<<<172, 256, 0, stream>>>(u, scal, labels, out + O_PSE, plab, Nc);

    offs_scan<<<1, 64, 0, stream>>>(Nc, offs);
    scatter_rows<<<172, 256, 0, stream>>>(plab, offs, fill, rlist);
    sinkhorn_fused<<<NCLSC, 256, 0, stream>>>(out + O_LOG, offs, rlist, qseg);
    pnew_partial<<<dim3((NTOK + PWIN - 1) / PWIN, 3), 256, 0, stream>>>(
        X, invn, qseg, offs, rlist, plab, Pnew);
    proto_out<<<(CC * KP * DIMC + 255) / 256, 256, 0, stream>>>(proto, Pnew, pres, out + O_PRO);
}

// Round 10
// 598.955 us; speedup vs baseline: 1.3910x; 1.3910x over previous
//
#include <hip/hip_runtime.h>

constexpr int   BB    = 32;
constexpr int   NPP   = 1369;
constexpr int   DIMC  = 768;
constexpr int   NCLSC = 200;
constexpr int   KP    = 5;
constexpr int   CC    = 201;
constexpr int   CKC   = 1005;
constexpr int   NPAD  = 1024;              // padded proto rows for MFMA tiles
constexpr int   NTOK  = BB * NPP;          // 43808
constexpr float EPSF  = 1e-8f;
constexpr int   PWIN  = 128;               // pnew row window
constexpr int   MTILES = 343;              // ceil(43808/128)
constexpr int   NSLAB = 4;                 // atomic-spread slabs

typedef __attribute__((ext_vector_type(8))) short bf16x8;
typedef __attribute__((ext_vector_type(4))) float f32x4;

// ---- output layout (float units) ----
constexpr size_t O_LOG = 0;
constexpr size_t O_IMG = (size_t)NTOK * CKC;
constexpr size_t O_CLS = O_IMG + (size_t)BB * CKC;
constexpr size_t O_PSE = O_CLS + (size_t)BB * NCLSC;
constexpr size_t O_PRO = O_PSE + (size_t)NTOK;

// ---- ws layout (float units; doubles at even offsets) ----
constexpr size_t W_PRONBF = 0;                               // ushort[1024*768]
constexpr size_t W_INVN   = W_PRONBF + (size_t)NPAD*DIMC/2;  // float[NTOK]
constexpr size_t W_MU     = W_INVN + NTOK;                   // double[768]
constexpr size_t W_COLS   = W_MU + 2*DIMC;                   // double[4*768] zero-group start
constexpr size_t W_VBUF   = W_COLS + 2*NSLAB*DIMC;           // double[11*4*768]
constexpr size_t W_SSUM   = W_VBUF + 2*11*NSLAB*DIMC;        // double[64]
constexpr size_t W_TSUM   = W_SSUM + 128;                    // float[201]
constexpr size_t W_NC     = W_TSUM + CC;                     // int[201]
constexpr size_t W_FILL   = W_NC + CC;                       // int[201]
constexpr size_t W_PRES   = W_FILL + CC;                     // int[201]
constexpr size_t ZG_LEN   = (W_PRES + CC) - W_COLS;
constexpr size_t W_CSQ    = W_PRES + CC;                     // float[1005] (unused)
constexpr size_t W_U      = ((W_CSQ + CKC) + 1) & ~(size_t)1;// double[NTOK]
constexpr size_t W_PART   = W_U + 2*NTOK;                    // double[1536]
constexpr size_t W_SCAL   = W_PART + 2*1536;                 // double[8]
constexpr size_t W_Q      = W_SCAL + 16;                     // float[NTOK*5] (segment-ordered)
constexpr size_t W_PNEW   = W_Q + (size_t)NTOK*KP;           // float[201*5*768]
constexpr size_t W_PLAB   = W_PNEW + (size_t)CC*KP*DIMC;     // int[NTOK]
constexpr size_t W_OFFS   = W_PLAB + NTOK;                   // int[256]
constexpr size_t W_RLST   = W_OFFS + 256;                    // int[NTOK]
constexpr size_t W_XBF    = ((W_RLST + NTOK) + 3) & ~(size_t)3; // ushort[(NTOK+128)*768]
constexpr size_t W_END_BIG  = W_XBF + (size_t)(NTOK + 128)*DIMC/2;
constexpr size_t W_PRON32   = W_XBF;                          // float[CKC*768] (fallback)
constexpr size_t W_END_FALL = W_PRON32 + (size_t)CKC*DIMC;

__device__ __forceinline__ unsigned short f2bf(float x) {
    unsigned u = __float_as_uint(x);
    unsigned r = (u + 0x7fffu + ((u >> 16) & 1u)) >> 16;   // RNE
    return (unsigned short)r;
}

// async global->LDS, 16B per lane; LDS dest must be wave-uniform base
typedef __attribute__((address_space(3))) unsigned int as3_u32;
typedef __attribute__((address_space(1))) unsigned int as1_u32;
__device__ __forceinline__ void gload16(const unsigned short* g, unsigned short* l) {
    __builtin_amdgcn_global_load_lds((as1_u32*)g, (as3_u32*)l, 16, 0, 0);
}

__global__ void fill_zero(float* p, int n) {
    int i = blockIdx.x * 256 + threadIdx.x;
    if (i < n) p[i] = 0.0f;
}

// per-row 1/clip(||x||) + fp64 column sums (wave-combined, 4-slab) + bf16 copy
__global__ __launch_bounds__(256) void tok_stats(const float* __restrict__ X,
                                                 float* __restrict__ invn,
                                                 double* __restrict__ colsD,
                                                 unsigned short* __restrict__ xbf) {
    __shared__ double csh[4][768];
    const int tid  = threadIdx.x;
    const int lane = tid & 63;
    const int wid  = tid >> 6;
    const int gw   = blockIdx.x * 4 + wid;
    double cacc[3][4];
    #pragma unroll
    for (int j = 0; j < 3; j++)
        #pragma unroll
        for (int t = 0; t < 4; t++) cacc[j][t] = 0.0;
    for (int n = gw; n < NTOK; n += 4096) {
        const float4* row = (const float4*)(X + (size_t)n * DIMC);
        float s = 0.0f;
        float4 xv[3];
        #pragma unroll
        for (int j = 0; j < 3; j++) {
            xv[j] = row[lane + 64*j];
            s = fmaf(xv[j].x, xv[j].x, s); s = fmaf(xv[j].y, xv[j].y, s);
            s = fmaf(xv[j].z, xv[j].z, s); s = fmaf(xv[j].w, xv[j].w, s);
            cacc[j][0] += (double)xv[j].x; cacc[j][1] += (double)xv[j].y;
            cacc[j][2] += (double)xv[j].z; cacc[j][3] += (double)xv[j].w;
        }
        if (xbf) {
            unsigned short* orow = xbf + (size_t)n * DIMC;
            #pragma unroll
            for (int j = 0; j < 3; j++) {
                ushort4 pk;
                pk.x = f2bf(xv[j].x); pk.y = f2bf(xv[j].y);
                pk.z = f2bf(xv[j].z); pk.w = f2bf(xv[j].w);
                *(ushort4*)(orow + 4*(lane + 64*j)) = pk;
            }
        }
        #pragma unroll
        for (int o = 32; o >= 1; o >>= 1) s += __shfl_xor(s, o);
        if (lane == 0) invn[n] = 1.0f / fmaxf(sqrtf(s), EPSF);
    }
    #pragma unroll
    for (int j = 0; j < 3; j++)
        #pragma unroll
        for (int t = 0; t < 4; t++)
            csh[wid][4*lane + 256*j + t] = cacc[j][t];
    __syncthreads();
    const int slab = blockIdx.x & (NSLAB - 1);
    for (int c = tid; c < 768; c += 256)
        atomicAdd(&colsD[slab * 768 + c], csh[0][c] + csh[1][c] + csh[2][c] + csh[3][c]);
}

// normalize prototypes -> bf16 (padded rows zeroed) and optional f32 copy
__global__ __launch_bounds__(256) void proto_norm(const float* __restrict__ P,
                                                  unsigned short* __restrict__ pbf,
                                                  float* __restrict__ p32) {
    const int lane = threadIdx.x & 63;
    const int gw   = blockIdx.x * 4 + (threadIdx.x >> 6);
    for (int j = gw; j < NPAD; j += 256) {
        unsigned short* obf = pbf + (size_t)j * DIMC;
        if (j >= CKC) {
            #pragma unroll
            for (int t = 0; t < 12; t++) obf[lane + 64*t] = 0;
            continue;
        }
        const float* row = P + (size_t)j * DIMC;
        float x[12]; float s = 0.0f;
        #pragma unroll
        for (int t = 0; t < 12; t++) { x[t] = row[lane + 64*t]; s = fmaf(x[t], x[t], s); }
        #pragma unroll
        for (int o = 32; o >= 1; o >>= 1) s += __shfl_xor(s, o);
        float nrm = fmaxf(sqrtf(s), EPSF);
        #pragma unroll
        for (int t = 0; t < 12; t++) {
            float nv = x[t] / nrm;
            obf[lane + 64*t] = f2bf(nv);
            if (p32) p32[(size_t)j * DIMC + lane + 64*t] = nv;
        }
    }
}

// Tiled bf16 MFMA GEMM with global_load_lds staging + chunk XOR-swizzle
// (rule #21: linear LDS dest, inverse-swizzled global src, swizzled read).
// 128x128 tile, BK=32, 4 waves, chunked XCD swizzle.
__global__ __launch_bounds__(256) void logits_gemm(
        const unsigned short* __restrict__ Xbf,
        const unsigned short* __restrict__ Pbf,
        const float* __restrict__ invn,
        const float* __restrict__ scale_p,
        float* __restrict__ out,
        float* __restrict__ img) {
    __shared__ unsigned short As[128 * 32];
    __shared__ unsigned short Bs[128 * 32];
    const int b   = blockIdx.x;                 // 0..2743
    const int swz = (b & 7) * MTILES + (b >> 3);  // bijective: 2744 = 8*343
    const int row_t = swz >> 3, col_t = swz & 7;
    const int row0 = row_t * 128, col0 = col_t * 128;
    const int tid = threadIdx.x, lane = tid & 63, wid = tid >> 6;
    const int wm = (wid >> 1) * 64, wn = (wid & 1) * 64;
    const int fr = lane & 15, fq = lane >> 4;

    f32x4 acc[4][4] = {};

    // staging: wave wid stages rows [wid*32, wid*32+32); lane covers row
    // w32+lane/4, physical 16B chunk (lane&3). Global k-chunk is XOR-swizzled
    // so the LDS read (same XOR) is bank-conflict-free (2-way worst case).
    const int w32 = wid * 32;
    const int lrow = lane >> 2;
    const int gch = ((lane & 3) ^ ((lrow ^ (lrow >> 2)) & 3)) * 8;
    const unsigned short* aS0 = Xbf + (size_t)(row0 + w32 + lrow) * DIMC + gch;
    const unsigned short* aS1 = aS0 + (size_t)16 * DIMC;
    const unsigned short* bS0 = Pbf + (size_t)(col0 + w32 + lrow) * DIMC + gch;
    const unsigned short* bS1 = bS0 + (size_t)16 * DIMC;
    unsigned short* aD0 = &As[(w32)      * 32];
    unsigned short* aD1 = &As[(w32 + 16) * 32];
    unsigned short* bD0 = &Bs[(w32)      * 32];
    unsigned short* bD1 = &Bs[(w32 + 16) * 32];

    // read-side swizzled chunk (row ≡ fr mod 16; swz depends only on fr bits)
    const int rc = (fq ^ ((fr ^ (fr >> 2)) & 3)) * 8;

    for (int ks = 0; ks < DIMC / 32; ks++) {
        __syncthreads();                      // prior reads done before overwrite
        gload16(aS0 + ks * 32, aD0);
        gload16(aS1 + ks * 32, aD1);
        gload16(bS0 + ks * 32, bD0);
        gload16(bS1 + ks * 32, bD1);
        __syncthreads();                      // drains vmcnt -> LDS ready
        bf16x8 af[4], bfr[4];
        #pragma unroll
        for (int m = 0; m < 4; m++)
            af[m] = *(const bf16x8*)(As + (wm + m * 16 + fr) * 32 + rc);
        #pragma unroll
        for (int n = 0; n < 4; n++)
            bfr[n] = *(const bf16x8*)(Bs + (wn + n * 16 + fr) * 32 + rc);
        #pragma unroll
        for (int m = 0; m < 4; m++)
            #pragma unroll
            for (int n = 0; n < 4; n++)
                acc[m][n] = __builtin_amdgcn_mfma_f32_16x16x32_bf16(af[m], bfr[n], acc[m][n], 0, 0, 0);
    }

    const float sc = *scale_p;
    #pragma unroll
    for (int m = 0; m < 4; m++) {
        const int rbase = row0 + wm + m * 16 + fq * 4;
        float fin[4];
        #pragma unroll
        for (int rr = 0; rr < 4; rr++) {
            int rrow = rbase + rr;
            fin[rr] = (rrow < NTOK) ? sc * invn[rrow] : 0.0f;
        }
        const int strip0 = row0 + wm + m * 16;
        const bool sameImg = ((strip0 / NPP) == ((strip0 + 15) / NPP)) && (strip0 + 15) < NTOK;
        const int bimg = strip0 / NPP;
        #pragma unroll
        for (int n = 0; n < 4; n++) {
            const int col = col0 + wn + n * 16 + fr;
            const bool cok = col < CKC;
            float csum = 0.0f;
            #pragma unroll
            for (int rr = 0; rr < 4; rr++) {
                int rrow = rbase + rr;
                float v = fin[rr] * acc[m][n][rr];
                if (cok && rrow < NTOK) out[(size_t)rrow * CKC + col] = v;
                csum += v;
            }
            if (sameImg) {
                csum += __shfl_xor(csum, 16);
                csum += __shfl_xor(csum, 32);
                if (lane < 16 && cok) atomicAdd(&img[bimg * CKC + col], csum);
            } else if (cok) {
                #pragma unroll
                for (int rr = 0; rr < 4; rr++) {
                    int rrow = rbase + rr;
                    if (rrow < NTOK)
                        atomicAdd(&img[(rrow / NPP) * CKC + col], fin[rr] * acc[m][n][rr]);
                }
            }
        }
    }
}

// fallback fp32 GEMM (used only when ws too small for Xbf)
__global__ __launch_bounds__(256) void gemm_logits(const float* __restrict__ X,
                                                   const float* __restrict__ Bn,
                                                   const float* __restrict__ invn,
                                                   const float* __restrict__ scale_p,
                                                   float* __restrict__ out) {
    __shared__ float As[32][68];
    __shared__ float Bs[32][68];
    const int tid = threadIdx.x;
    const int tx = tid & 15, ty = tid >> 4;
    const int row0 = blockIdx.x * 64;
    const int col0 = blockIdx.y * 64;
    const int lm = tid >> 2;
    const int kb = (tid & 3) * 8;
    float acc[4][4] = {};
    for (int k0 = 0; k0 < DIMC; k0 += 32) {
        float a[8], b[8];
        int ar = row0 + lm;
        if (ar < NTOK) {
            const float* ap = X + (size_t)ar * DIMC + k0 + kb;
            #pragma unroll
            for (int j = 0; j < 8; j++) a[j] = ap[j];
        } else {
            #pragma unroll
            for (int j = 0; j < 8; j++) a[j] = 0.0f;
        }
        int bc = col0 + lm;
        if (bc < CKC) {
            const float* bp = Bn + (size_t)bc * DIMC + k0 + kb;
            #pragma unroll
            for (int j = 0; j < 8; j++) b[j] = bp[j];
        } else {
            #pragma unroll
            for (int j = 0; j < 8; j++) b[j] = 0.0f;
        }
        __syncthreads();
        #pragma unroll
        for (int j = 0; j < 8; j++) As[kb + j][lm] = a[j];
        #pragma unroll
        for (int j = 0; j < 8; j++) Bs[kb + j][lm] = b[j];
        __syncthreads();
        #pragma unroll
        for (int kk = 0; kk < 32; kk++) {
            float av[4], bv[4];
            #pragma unroll
            for (int i = 0; i < 4; i++) av[i] = As[kk][ty*4 + i];
            #pragma unroll
            for (int j = 0; j < 4; j++) bv[j] = Bs[kk][tx*4 + j];
            #pragma unroll
            for (int i = 0; i < 4; i++)
                #pragma unroll
                for (int j = 0; j < 4; j++)
                    acc[i][j] = fmaf(av[i], bv[j], acc[i][j]);
        }
    }
    const float sc = *scale_p;
    #pragma unroll
    for (int i = 0; i < 4; i++) {
        int r = row0 + ty*4 + i;
        if (r >= NTOK) continue;
        float f = sc * invn[r];
        float* orow = out + (size_t)r * CKC;
        #pragma unroll
        for (int j = 0; j < 4; j++) {
            int c = col0 + tx*4 + j;
            if (c < CKC) orow[c] = f * acc[i][j];
        }
    }
}

__global__ void img_reduce(const float* __restrict__ logits, float* __restrict__ img) {
    int b = blockIdx.x, jc = blockIdx.y, nc = blockIdx.z;
    int j = jc * 256 + threadIdx.x;
    if (j >= CKC) return;
    int p0 = nc * 172, p1 = min(NPP, p0 + 172);
    const float* base = logits + (size_t)b * NPP * CKC + j;
    float s = 0.0f;
    for (int p = p0; p < p1; p++) s += base[(size_t)p * CKC];
    atomicAdd(&img[b * CKC + j], s);
}

__global__ __launch_bounds__(256) void img_final(float* __restrict__ img,
                                                 const float* __restrict__ sa,
                                                 float* __restrict__ cls) {
    int b = blockIdx.x;
    for (int i = threadIdx.x; i < CKC; i += 256)
        img[b * CKC + i] = img[b * CKC + i] / 1369.0f;
    __syncthreads();
    for (int c = threadIdx.x; c < NCLSC; c += 256) {
        float vv[KP]; float mx = -3.4e38f;
        #pragma unroll
        for (int k = 0; k < KP; k++) { vv[k] = sa[c * KP + k]; mx = fmaxf(mx, vv[k]); }
        float e[KP]; float s = 0.0f;
        #pragma unroll
        for (int k = 0; k < KP; k++) { e[k] = expf(vv[k] - mx); s += e[k]; }
        float cl = 0.0f;
        #pragma unroll
        for (int k = 0; k < KP; k++) {
            float sw = e[k] / s * 5.0f;
            cl += img[b * CKC + c * KP + k] * sw;
        }
        cls[b * NCLSC + c] = cl;
    }
}

__global__ void mu_final(const double* __restrict__ colsD, double* __restrict__ mu) {
    int d = threadIdx.x;
    mu[d] = (colsD[d] + colsD[768 + d] + colsD[1536 + d] + colsD[2304 + d]) / (double)NTOK;
}

// XLA uniform(lo=-0.99999994,hi=1) -> sqrt(2)*erfinv (Giles/XLA f32 polynomial)
__device__ __forceinline__ float bits_to_normal(unsigned bits) {
    float f = __uint_as_float((bits >> 9) | 0x3f800000u) - 1.0f;
    const float lo = -0.99999994f;
    float u = f * 2.0f + lo;
    u = fmaxf(lo, u);
    float w = -log1pf(-u * u);
    float p;
    if (w < 5.0f) {
        w -= 2.5f;
        p = 2.81022636e-08f;
        p = fmaf(p, w, 3.43273939e-07f);
        p = fmaf(p, w, -3.5233877e-06f);
        p = fmaf(p, w, -4.39150654e-06f);
        p = fmaf(p, w, 0.00021858087f);
        p = fmaf(p, w, -0.00125372503f);
        p = fmaf(p, w, -0.00417768164f);
        p = fmaf(p, w, 0.246640727f);
        p = fmaf(p, w, 1.50140941f);
    } else {
        w = sqrtf(w) - 3.0f;
        p = -0.000200214257f;
        p = fmaf(p, w, 0.000100950558f);
        p = fmaf(p, w, 0.00134934322f);
        p = fmaf(p, w, -0.00367342844f);
        p = fmaf(p, w, 0.00573950773f);
        p = fmaf(p, w, -0.0076224613f);
        p = fmaf(p, w, 0.00943887047f);
        p = fmaf(p, w, 1.00167406f);
        p = fmaf(p, w, 2.83297682f);
    }
    return 1.41421356237f * (p * u);
}

// jax threefry_partitionable, 32-bit: counter (hi=0, lo=i), sample = out0 ^ out1
#define TF_ROUND(r) { x0 += x1; x1 = (x1 << r) | (x1 >> (32 - r)); x1 ^= x0; }
__global__ void v0_gen(double* __restrict__ v) {
    int i = blockIdx.x * 256 + threadIdx.x;
    if (i >= DIMC) return;
    unsigned x0 = 0u, x1 = (unsigned)i;
    const unsigned k0 = 0u, k1 = 42u, k2 = k0 ^ k1 ^ 0x1BD11BDAu;
    x0 += k0; x1 += k1;
    TF_ROUND(13) TF_ROUND(15) TF_ROUND(26) TF_ROUND(6)
    x0 += k1; x1 += k2 + 1u;
    TF_ROUND(17) TF_ROUND(29) TF_ROUND(16) TF_ROUND(24)
    x0 += k2; x1 += k0 + 2u;
    TF_ROUND(13) TF_ROUND(15) TF_ROUND(26) TF_ROUND(6)
    x0 += k0; x1 += k1 + 3u;
    TF_ROUND(17) TF_ROUND(29) TF_ROUND(16) TF_ROUND(24)
    x0 += k1; x1 += k2 + 4u;
    TF_ROUND(13) TF_ROUND(15) TF_ROUND(26) TF_ROUND(6)
    x0 += k2; x1 += k0 + 5u;
    v[i] = (double)bits_to_normal(x0 ^ x1);
}

// One Gram application: u = Xc*v_eff ; vnext += Xc^T u (fp64 acc).
// vraw/Sin are 4-slab accumulators from the previous pass; output goes into
// slab (blockIdx & 3) -> per-address atomic chains of 128 instead of 512.
// float4 loads, reg-held ve, 2-row unroll for MLP.
__global__ __launch_bounds__(256) void pca_pass(const float* __restrict__ X,
                                                const double* __restrict__ mu,
                                                const double* __restrict__ vraw,
                                                const double* __restrict__ Sin,
                                                double* __restrict__ vnext,
                                                double* __restrict__ Snext) {
    __shared__ double wacc[4][768];
    __shared__ double redw[4];
    const int tid = threadIdx.x, lane = tid & 63, wid = tid >> 6;
    const double S = Sin[0] + Sin[1] + Sin[2] + Sin[3];
    double ver[3][4];
    double mv = 0.0;
    #pragma unroll
    for (int j = 0; j < 3; j++)
        #pragma unroll
        for (int t = 0; t < 4; t++) {
            int c = 4*lane + 256*j + t;
            double x = (vraw[c] + vraw[768 + c] + vraw[1536 + c] + vraw[2304 + c]) - S * mu[c];
            ver[j][t] = x;
            mv += mu[c] * x;
        }
    #pragma unroll
    for (int o = 32; o >= 1; o >>= 1) mv += __shfl_xor(mv, o);
    const double muv = mv;

    double acc[3][4] = {};
    double usum = 0.0;
    const int gw = blockIdx.x * 4 + wid;
    for (int n0 = gw; n0 < NTOK; n0 += 4096) {
        const int n1 = n0 + 2048;
        const bool h1 = (n1 < NTOK);
        const float4* r0 = (const float4*)(X + (size_t)n0 * DIMC);
        const float4* r1 = (const float4*)(X + (size_t)(h1 ? n1 : n0) * DIMC);
        float4 xa[3], xb[3];
        #pragma unroll
        for (int j = 0; j < 3; j++) xa[j] = r0[lane + 64*j];
        #pragma unroll
        for (int j = 0; j < 3; j++) xb[j] = r1[lane + 64*j];
        double s0 = 0.0, s1 = 0.0;
        #pragma unroll
        for (int j = 0; j < 3; j++) {
            s0 = fma((double)xa[j].x, ver[j][0], s0);
            s0 = fma((double)xa[j].y, ver[j][1], s0);
            s0 = fma((double)xa[j].z, ver[j][2], s0);
            s0 = fma((double)xa[j].w, ver[j][3], s0);
            s1 = fma((double)xb[j].x, ver[j][0], s1);
            s1 = fma((double)xb[j].y, ver[j][1], s1);
            s1 = fma((double)xb[j].z, ver[j][2], s1);
            s1 = fma((double)xb[j].w, ver[j][3], s1);
        }
        #pragma unroll
        for (int o = 32; o >= 1; o >>= 1) { s0 += __shfl_xor(s0, o); s1 += __shfl_xor(s1, o); }
        double uu0 = s0 - muv;
        usum += uu0;
        #pragma unroll
        for (int j = 0; j < 3; j++) {
            acc[j][0] = fma((double)xa[j].x, uu0, acc[j][0]);
            acc[j][1] = fma((double)xa[j].y, uu0, acc[j][1]);
            acc[j][2] = fma((double)xa[j].z, uu0, acc[j][2]);
            acc[j][3] = fma((double)xa[j].w, uu0, acc[j][3]);
        }
        if (h1) {
            double uu1 = s1 - muv;
            usum += uu1;
            #pragma unroll
            for (int j = 0; j < 3; j++) {
                acc[j][0] = fma((double)xb[j].x, uu1, acc[j][0]);
                acc[j][1] = fma((double)xb[j].y, uu1, acc[j][1]);
                acc[j][2] = fma((double)xb[j].z, uu1, acc[j][2]);
                acc[j][3] = fma((double)xb[j].w, uu1, acc[j][3]);
            }
        }
    }
    #pragma unroll
    for (int j = 0; j < 3; j++)
        #pragma unroll
        for (int t = 0; t < 4; t++)
            wacc[wid][4*lane + 256*j + t] = acc[j][t];
    if (lane == 0) redw[wid] = usum;
    __syncthreads();
    const int slab = blockIdx.x & (NSLAB - 1);
    for (int c = tid; c < 768; c += 256)
        atomicAdd(&vnext[slab * 768 + c], wacc[0][c] + wacc[1][c] + wacc[2][c] + wacc[3][c]);
    if (tid == 0) atomicAdd(&Snext[slab], redw[0] + redw[1] + redw[2] + redw[3]);
}

// final u = Xc*v_eff + per-block min/max/sumsq partials (slab-summed input)
__global__ __launch_bounds__(256) void u_final(const float* __restrict__ X,
                                               const double* __restrict__ mu,
                                               const double* __restrict__ vraw,
                                               const double* __restrict__ Sin,
                                               double* __restrict__ u,
                                               double* __restrict__ part) {
    __shared__ double wmin[4], wmax[4], wss[4];
    const int tid = threadIdx.x, lane = tid & 63, wid = tid >> 6;
    const double S = Sin[0] + Sin[1] + Sin[2] + Sin[3];
    double ver[3][4];
    double mv = 0.0;
    #pragma unroll
    for (int j = 0; j < 3; j++)
        #pragma unroll
        for (int t = 0; t < 4; t++) {
            int c = 4*lane + 256*j + t;
            double x = (vraw[c] + vraw[768 + c] + vraw[1536 + c] + vraw[2304 + c]) - S * mu[c];
            ver[j][t] = x;
            mv += mu[c] * x;
        }
    #pragma unroll
    for (int o = 32; o >= 1; o >>= 1) mv += __shfl_xor(mv, o);
    const double muv = mv;
    double lmin = 1e300, lmax = -1e300, lss = 0.0;
    for (int n = blockIdx.x * 4 + wid; n < NTOK; n += 2048) {
        const float4* row = (const float4*)(X + (size_t)n * DIMC);
        double s = 0.0;
        #pragma unroll
        for (int j = 0; j < 3; j++) {
            float4 xv = row[lane + 64*j];
            s = fma((double)xv.x, ver[j][0], s);
            s = fma((double)xv.y, ver[j][1], s);
            s = fma((double)xv.z, ver[j][2], s);
            s = fma((double)xv.w, ver[j][3], s);
        }
        #pragma unroll
        for (int o = 32; o >= 1; o >>= 1) s += __shfl_xor(s, o);
        double uu = s - muv;
        if (lane == 0) {
            u[n] = uu;
            lmin = fmin(lmin, uu); lmax = fmax(lmax, uu); lss = fma(uu, uu, lss);
        }
    }
    if (lane == 0) { wmin[wid] = lmin; wmax[wid] = lmax; wss[wid] = lss; }
    __syncthreads();
    if (tid == 0) {
        part[blockIdx.x]        = fmin(fmin(wmin[0], wmin[1]), fmin(wmin[2], wmin[3]));
        part[512 + blockIdx.x]  = fmax(fmax(wmax[0], wmax[1]), fmax(wmax[2], wmax[3]));
        part[1024 + blockIdx.x] = wss[0] + wss[1] + wss[2] + wss[3];
    }
}

__global__ __launch_bounds__(512) void final_scalars(const double* __restrict__ part,
                                                     double* __restrict__ scal,
                                                     const int* __restrict__ labels,
                                                     int* __restrict__ pres) {
    __shared__ double rmin[512], rmax[512], rss[512];
    int t = threadIdx.x;
    rmin[t] = part[t]; rmax[t] = part[512 + t]; rss[t] = part[1024 + t];
    __syncthreads();
    for (int s = 256; s > 0; s >>= 1) {
        if (t < s) {
            rmin[t] = fmin(rmin[t], rmin[t + s]);
            rmax[t] = fmax(rmax[t], rmax[t + s]);
            rss[t] += rss[t + s];
        }
        __syncthreads();
    }
    if (t == 0) {
        double nrm = fmax(sqrt(rss[0]), 1e-8);
        double Umin = rmin[0] / nrm;
        double Umax = rmax[0] / nrm;
        scal[1] = nrm;
        scal[2] = Umin;
        scal[3] = fmax(Umax - Umin, 1e-8);
    }
    if (t < BB) pres[labels[t]] = 1;
}

// pseudo labels + LDS-aggregated class histogram
__global__ __launch_bounds__(256) void pseudo_kernel(
        const double* __restrict__ u, const double* __restrict__ scal,
        const int* __restrict__ labels, float* __restrict__ pse,
        int* __restrict__ plab, int* __restrict__ Nc) {
    __shared__ int hist[CC];
    const int tid = threadIdx.x;
    for (int c = tid; c < CC; c += 256) hist[c] = 0;
    __syncthreads();
    int n = blockIdx.x * 256 + tid;
    if (n < NTOK) {
        double U  = u[n] / scal[1];
        double Us = (U - scal[2]) / scal[3];
        int lab = (Us <= 0.5) ? labels[n / NPP] : (CC - 1);
        pse[n] = (float)lab;
        plab[n] = lab;
        atomicAdd(&hist[lab], 1);
    }
    __syncthreads();
    for (int c = tid; c < CC; c += 256)
        if (hist[c] > 0) atomicAdd(&Nc[c], hist[c]);
}

__global__ void offs_scan(const int* __restrict__ Nc, int* __restrict__ offs) {
    if (threadIdx.x == 0) {
        int s = 0;
        for (int c = 0; c < CC; c++) { offs[c] = s; s += Nc[c]; }
        offs[CC] = s;
    }
}

// LDS-aggregated scatter
__global__ __launch_bounds__(256) void scatter_rows(
        const int* __restrict__ plab, const int* __restrict__ offs,
        int* __restrict__ fill, int* __restrict__ rlist) {
    __shared__ int hist[CC];
    __shared__ int base[CC];
    const int tid = threadIdx.x;
    for (int c = tid; c < CC; c += 256) hist[c] = 0;
    __syncthreads();
    int n = blockIdx.x * 256 + tid;
    int lab = -1, posl = 0;
    if (n < NTOK) {
        lab = plab[n];
        posl = atomicAdd(&hist[lab], 1);
    }
    __syncthreads();
    for (int c = tid; c < CC; c += 256) {
        int h = hist[c];
        if (h > 0) base[c] = atomicAdd(&fill[c], h);
    }
    __syncthreads();
    if (n < NTOK) rlist[offs[lab] + base[lab] + posl] = n;
}

// One block per fg class: fused sinkhorn over the class's qseg slice
__global__ __launch_bounds__(256) void sinkhorn_fused(
        const float* __restrict__ logits,
        const int* __restrict__ offs,
        const int* __restrict__ rlist,
        float* __restrict__ qseg) {
    const int c  = blockIdx.x;           // 0..NCLSC-1 (background excluded)
    const int i0 = offs[c], i1 = offs[c + 1];
    const int cnt = i1 - i0;
    if (cnt <= 0) return;
    const int tid = threadIdx.x;
    __shared__ float cs[KP];
    __shared__ float redk[KP][4];

    for (int i = i0 + tid; i < i1; i += 256) {
        int n = rlist[i];
        const float* lp = logits + (size_t)n * CKC + c * KP;
        #pragma unroll
        for (int k = 0; k < KP; k++) qseg[(size_t)i * KP + k] = expf(lp[k]);
    }
    const float Ncc = fmaxf((float)cnt, 1.0f);
    for (int it = 0; it < 3; it++) {
        __syncthreads();
        float lc[KP] = {};
        for (int i = i0 + tid; i < i1; i += 256) {
            #pragma unroll
            for (int k = 0; k < KP; k++) lc[k] += qseg[(size_t)i * KP + k];
        }
        #pragma unroll
        for (int k = 0; k < KP; k++) {
            float v = lc[k];
            #pragma unroll
            for (int o = 32; o >= 1; o >>= 1) v += __shfl_xor(v, o);
            if ((tid & 63) == 0) redk[k][tid >> 6] = v;
        }
        __syncthreads();
        if (tid == 0) {
            #pragma unroll
            for (int k = 0; k < KP; k++)
                cs[k] = fmaxf(redk[k][0] + redk[k][1] + redk[k][2] + redk[k][3], EPSF) * 5.0f;
        }
        __syncthreads();
        float inv_cs[KP];
        #pragma unroll
        for (int k = 0; k < KP; k++) inv_cs[k] = 1.0f / cs[k];
        const float outsc = (it == 2) ? ((float)cnt / Ncc) : (1.0f / Ncc);
        for (int i = i0 + tid; i < i1; i += 256) {
            float v[KP]; float rs = 0.0f;
            #pragma unroll
            for (int k = 0; k < KP; k++) { v[k] = qseg[(size_t)i*KP + k] * inv_cs[k]; rs += v[k]; }
            float f = outsc / fmaxf(rs, EPSF);
            #pragma unroll
            for (int k = 0; k < KP; k++) qseg[(size_t)i*KP + k] = v[k] * f;
        }
    }
}

// Windowed segmented P_new accumulation.
__global__ __launch_bounds__(256) void pnew_partial(
        const float* __restrict__ X,
        const float* __restrict__ invn,
        const float* __restrict__ qseg,
        const int* __restrict__ offs,
        const int* __restrict__ rlist,
        const int* __restrict__ plab,
        float* __restrict__ Pnew) {
    const int d = blockIdx.y * 256 + threadIdx.x;
    const int fgEnd = offs[CC - 1];
    int i0 = blockIdx.x * PWIN;
    if (i0 >= fgEnd) return;
    int i1 = min(i0 + PWIN, fgEnd);
    int curlab = -1;
    float acc[KP] = {};
    for (int i = i0; i < i1; i++) {
        int n = rlist[i];
        int lab = plab[n];
        if (lab != curlab) {
            if (curlab >= 0) {
                #pragma unroll
                for (int k = 0; k < KP; k++)
                    atomicAdd(&Pnew[((size_t)curlab * KP + k) * DIMC + d], acc[k]);
            }
            curlab = lab;
            #pragma unroll
            for (int k = 0; k < KP; k++) acc[k] = 0.0f;
        }
        float x = X[(size_t)n * DIMC + d] * invn[n];
        #pragma unroll
        for (int k = 0; k < KP; k++) acc[k] = fmaf(qseg[(size_t)i * KP + k], x, acc[k]);
    }
    if (curlab >= 0) {
        #pragma unroll
        for (int k = 0; k < KP; k++)
            atomicAdd(&Pnew[((size_t)curlab * KP + k) * DIMC + d], acc[k]);
    }
}

__global__ void proto_out(const float* __restrict__ proto, const float* __restrict__ Pnew,
                          const int* __restrict__ pres, float* __restrict__ outp) {
    int idx = blockIdx.x * 256 + threadIdx.x;
    if (idx >= CC * KP * DIMC) return;
    int c = idx / (KP * DIMC);
    float p = proto[idx];
    float r = p;
    if (pres[c]) {
        const float g = 0.99f;
        r = g * p + (1.0f - g) * Pnew[idx];
    }
    outp[idx] = r;
}

extern "C" void kernel_launch(void* const* d_in, const int* in_sizes, int n_in,
                              void* d_out, int out_size, void* d_ws, size_t ws_size,
                              hipStream_t stream) {
    const float* X      = (const float*)d_in[0];
    const int*   labels = (const int*)  d_in[1];
    const float* proto  = (const float*)d_in[2];
    const float* sa     = (const float*)d_in[3];
    const float* scale  = (const float*)d_in[4];
    float* out = (float*)d_out;
    float* ws  = (float*)d_ws;
    const bool big = ws_size >= W_END_BIG * sizeof(float);
    if (!big && ws_size < W_END_FALL * sizeof(float)) return;

    unsigned short* pronbf = (unsigned short*)(ws + W_PRONBF);
    float*  invn  = ws + W_INVN;
    double* mu    = (double*)(ws + W_MU);
    double* colsD = (double*)(ws + W_COLS);
    double* vbuf  = (double*)(ws + W_VBUF);
    double* Ssum  = (double*)(ws + W_SSUM);
    int*    Nc    = (int*)(ws + W_NC);
    int*    fill  = (int*)(ws + W_FILL);
    int*    pres  = (int*)(ws + W_PRES);
    double* u     = (double*)(ws + W_U);
    double* part  = (double*)(ws + W_PART);
    double* scal  = (double*)(ws + W_SCAL);
    float*  qseg  = ws + W_Q;
    float*  Pnew  = ws + W_PNEW;
    int*    plab  = (int*)(ws + W_PLAB);
    int*    offs  = (int*)(ws + W_OFFS);
    int*    rlist = (int*)(ws + W_RLST);
    unsigned short* xbf = big ? (unsigned short*)(ws + W_XBF) : nullptr;
    float*  pron32 = big ? nullptr : (ws + W_PRON32);

    // zero accumulators (ws is NOT re-poisoned between replays)
    fill_zero<<<((int)ZG_LEN + 255) / 256, 256, 0, stream>>>(ws + W_COLS, (int)ZG_LEN);
    fill_zero<<<(CC * KP * DIMC + 255) / 256, 256, 0, stream>>>(Pnew, CC * KP * DIMC);
    fill_zero<<<(BB * CKC + 255) / 256, 256, 0, stream>>>(out + O_IMG, BB * CKC);

    tok_stats<<<1024, 256, 0, stream>>>(X, invn, colsD, xbf);
    proto_norm<<<64, 256, 0, stream>>>(proto, pronbf, pron32);
    if (big) {
        logits_gemm<<<MTILES * 8, 256, 0, stream>>>(xbf, pronbf, invn, scale,
                                                    out + O_LOG, out + O_IMG);
    } else {
        gemm_logits<<<dim3(685, 16), 256, 0, stream>>>(X, pron32, invn, scale, out + O_LOG);
        img_reduce<<<dim3(32, 4, 8), 256, 0, stream>>>(out + O_LOG, out + O_IMG);
    }
    img_final<<<32, 256, 0, stream>>>(out + O_IMG, sa, out + O_CLS);

    mu_final<<<1, 768, 0, stream>>>(colsD, mu);
    v0_gen<<<3, 256, 0, stream>>>(vbuf);            // slab 0 of t=0 (rest zeroed)
    for (int t = 0; t < 10; t++) {
        pca_pass<<<512, 256, 0, stream>>>(X, mu,
            vbuf + (size_t)t * NSLAB * DIMC, Ssum + t * NSLAB,
            vbuf + (size_t)(t + 1) * NSLAB * DIMC, Ssum + (t + 1) * NSLAB);
    }
    u_final<<<512, 256, 0, stream>>>(X, mu,
        vbuf + (size_t)10 * NSLAB * DIMC, Ssum + 10 * NSLAB, u, part);
    final_scalars<<<1, 512, 0, stream>>>(part, scal, labels, pres);
    pseudo_kernel<<<172, 256, 0, stream>>>(u, scal, labels, out + O_PSE, plab, Nc);

    offs_scan<<<1, 64, 0, stream>>>(Nc, offs);
    scatter_rows<<<172, 256, 0, stream>>>(plab, offs, fill, rlist);
    sinkhorn_fused<<<NCLSC, 256, 0, stream>>>(out + O_LOG, offs, rlist, qseg);
    pnew_partial<<<dim3((NTOK + PWIN - 1) / PWIN, 3), 256, 0, stream>>>(
        X, invn, qseg, offs, rlist, plab, Pnew);
    proto_out<<<(CC * KP * DIMC + 255) / 256, 256, 0, stream>>>(proto, Pnew, pres, out + O_PRO);
}